// Round 6
// baseline (211.239 us; speedup 1.0000x reference)
//
#include <hip/hip_runtime.h>
#include <math.h>

// Problem constants: N=100000, S=64, Q=50, P=3
#define N_Q 50
#define N_S 64
#define ROW_F2 75      // 150 floats = 75 float2 per row
#define THREADS 256    // 4 waves; wave ws owns s in [16ws, 16ws+16)
#define BLK_ROWS 64    // 1 row per lane
#define APAD 26        // 24 floats (8-q window) + 2 pad; even -> b64 ok; 2-way alias = free
#define WIN_F2 12      // 24 floats per window = 12 float2
#define NWIN 6         // 6 windows x 8 q = 48, + tail 2 q

// ws layout (bytes):
//   [0..12504)   partials double[1563]
//   [12544..+4)  done-counter
//   [12608..+38400) HP float[50][64][3]  (q-major normalized heads)
//   [51008..+256)   hrv float[64]
#define WS_CNT_OFF 12544
#define WS_HP_OFF 12608
#define WS_HRV_OFF 51008

__device__ __forceinline__ float softplus20(float x) {
    float z = x * 20.0f;
    return fmaxf(z, 0.0f) + log1pf(expf(-fabsf(z)));  // stable softplus
}

__global__ void precompute_kernel(const float* __restrict__ heads_param,
                                  const float* __restrict__ hr_param,
                                  float* __restrict__ HP,
                                  float* __restrict__ hrv,
                                  int* __restrict__ cnt) {
    const int tid = threadIdx.x;
    if (blockIdx.x == 0) {
        if (tid == 0) *cnt = 0;  // ws re-poisoned every launch
        if (tid < N_S) {
            float sp = softplus20(hr_param[tid]);
            float tot = sp;
            #pragma unroll
            for (int off = 32; off; off >>= 1) tot += __shfl_xor(tot, off);
            hrv[tid] = (sp / fmaxf(tot, 1e-12f) + 0.001f / (float)N_S) / 1.001f;
        }
    }
    // EXACT reference semantics: h_p = sp_p / max(sum, EPS). When the clamp
    // fires the row does NOT sum to 1 -> all three components stored.
    int idx = blockIdx.x * blockDim.x + tid;
    if (idx < N_S * N_Q) {
        int q = idx >> 6, s = idx & 63;
        const float* hp = heads_param + ((size_t)s * N_Q + q) * 3;
        float sp0 = softplus20(hp[0]);
        float sp1 = softplus20(hp[1]);
        float sp2 = softplus20(hp[2]);
        float denom = fmaxf(sp0 + sp1 + sp2, 1e-12f);
        float* o = HP + ((size_t)q * N_S + s) * 3;
        o[0] = sp0 / denom; o[1] = sp1 / denom; o[2] = sp2 / denom;
    }
}

// Coalesced fetch of one 8-q window (64 rows x 12 float2) into registers.
__device__ __forceinline__ void fetch6(float2 (&r)[6], const float2* __restrict__ Af2,
                                       int nbase, int tid, int f2off, int N) {
    #pragma unroll
    for (int k = 0; k < 6; ++k) {
        int j = tid + THREADS * k;            // < 768
        int row = j / WIN_F2;
        int c2 = j - row * WIN_F2;
        int n = nbase + row;
        if (n >= N) n = N - 1;                // duplicate row, masked in epilogue
        r[k] = Af2[(size_t)n * ROW_F2 + f2off + c2];
    }
}

__device__ __forceinline__ void write6(const float2 (&r)[6], float* __restrict__ abuf,
                                       int tid) {
    #pragma unroll
    for (int k = 0; k < 6; ++k) {
        int j = tid + THREADS * k;
        int row = j / WIN_F2;
        int c2 = j - row * WIN_F2;
        *(float2*)&abuf[row * APAD + 2 * c2] = r[k];  // even offset -> b64 store
    }
}

// 16 s-values for one q. H floats are WAVE-UNIFORM -> SGPRs via SMEM;
// each fma reads exactly one SGPR (legal), A values are VGPRs from LDS.
__device__ __forceinline__ void computeQ(const float4* __restrict__ hq,
                                         float a0, float a1, float a2,
                                         float (&prod)[16]) {
    #pragma unroll
    for (int g = 0; g < 4; ++g) {
        // 4 s packed: [h00 h01 h02 h10][h11 h12 h20 h21][h22 h30 h31 h32]
        float4 b0 = hq[3*g], b1 = hq[3*g+1], b2 = hq[3*g+2];
        prod[4*g+0] *= fmaf(b0.x, a0, fmaf(b0.y, a1, b0.z * a2));
        prod[4*g+1] *= fmaf(b0.w, a0, fmaf(b1.x, a1, b1.y * a2));
        prod[4*g+2] *= fmaf(b1.z, a0, fmaf(b1.w, a1, b2.x * a2));
        prod[4*g+3] *= fmaf(b2.y, a0, fmaf(b2.z, a1, b2.w * a2));
    }
}

__global__ __launch_bounds__(THREADS) void main_kernel(
    const float* __restrict__ A, const float* __restrict__ coeff,
    const float* __restrict__ HP, const float* __restrict__ hrv,
    double* __restrict__ partials, int* __restrict__ cnt,
    float* __restrict__ out, int N) {
    __shared__ __align__(16) float ABUF[BLK_ROWS * APAD];  // 6656 B
    __shared__ float covs[4][BLK_ROWS];                    // 1024 B
    __shared__ double redd[4];
    __shared__ int isLast;
    // ~7.8 KB LDS -> residency capped by wave slots, not LDS

    const int tid = threadIdx.x;
    const int lane = tid & 63;
    const int ws = tid >> 6;
    const int nbase = blockIdx.x * BLK_ROWS;
    const float2* __restrict__ Af2 = (const float2*)A;

    // window 0 into LDS
    float2 st[6];
    fetch6(st, Af2, nbase, tid, 0, N);
    write6(st, ABUF, tid);
    __syncthreads();

    // uniform H base for this wave's 16-s slab -> SMEM path
    const int s0 = __builtin_amdgcn_readfirstlane(ws * 16);
    const float* __restrict__ Hb = HP + s0 * 3;
    const float* __restrict__ hrvb = hrv + s0;

    float prod[16];
    #pragma unroll
    for (int i = 0; i < 16; ++i) prod[i] = 1.0f;

    const float* arow = ABUF + lane * APAD;

    for (int w = 0; w < NWIN; ++w) {
        // prefetch next window into registers (vmcnt domain; lands during compute)
        float2 nx[6];
        float2 tl;
        int trow = 0, tc2 = 0;
        if (w < NWIN - 1) {
            fetch6(nx, Af2, nbase, tid, WIN_F2 * (w + 1), N);
        } else if (tid < 192) {            // tail: 2 q = 3 float2 per row
            trow = tid / 3; tc2 = tid - trow * 3;
            int n = nbase + trow; if (n >= N) n = N - 1;
            tl = Af2[(size_t)n * ROW_F2 + 72 + tc2];
        }

        #pragma unroll
        for (int qq = 0; qq < 8; ++qq) {
            const int q = 8 * w + qq;
            float a0 = arow[3 * qq + 0];
            float a1 = arow[3 * qq + 1];
            float a2 = arow[3 * qq + 2];
            computeQ((const float4*)(Hb + (size_t)q * (N_S * 3)), a0, a1, a2, prod);
        }
        __syncthreads();
        if (w < NWIN - 1) write6(nx, ABUF, tid);
        else if (tid < 192) *(float2*)&ABUF[trow * APAD + 2 * tc2] = tl;
        __syncthreads();
    }
    // tail q = 48, 49
    #pragma unroll
    for (int qq = 0; qq < 2; ++qq) {
        const int q = 48 + qq;
        float a0 = arow[3 * qq + 0];
        float a1 = arow[3 * qq + 1];
        float a2 = arow[3 * qq + 2];
        computeQ((const float4*)(Hb + (size_t)q * (N_S * 3)), a0, a1, a2, prod);
    }

    // ratio-weighted partial (hrv uniform -> SGPR)
    float acc = 0.0f;
    #pragma unroll
    for (int i = 0; i < 16; ++i) acc = fmaf(hrvb[i], prod[i], acc);
    covs[ws][lane] = acc;
    __syncthreads();

    if (ws == 0) {
        const int n = nbase + lane;
        float cov = covs[0][lane] + covs[1][lane] + covs[2][lane] + covs[3][lane];
        float term = 0.0f;
        if (n < N) { float c = coeff[n]; term = (c * c) / cov; }
        double td = (double)term;
        #pragma unroll
        for (int off = 32; off; off >>= 1) td += __shfl_down(td, off);
        if (lane == 0) {
            partials[blockIdx.x] = td;
            __threadfence();
            int v = atomicAdd(cnt, 1);
            isLast = (v == (int)gridDim.x - 1);
        }
    }
    __syncthreads();

    if (isLast) {                       // last-finishing block: final reduce
        __threadfence();
        double s = 0.0;
        for (int i = tid; i < (int)gridDim.x; i += THREADS) s += partials[i];
        #pragma unroll
        for (int off = 32; off; off >>= 1) s += __shfl_down(s, off);
        if (lane == 0) redd[ws] = s;
        __syncthreads();
        if (tid == 0) out[0] = (float)(redd[0] + redd[1] + redd[2] + redd[3]);
    }
}

extern "C" void kernel_launch(void* const* d_in, const int* in_sizes, int n_in,
                              void* d_out, int out_size, void* d_ws, size_t ws_size,
                              hipStream_t stream) {
    const float* A           = (const float*)d_in[0];  // [N, Q, P]
    const float* coeff       = (const float*)d_in[1];  // [N]
    const float* heads_param = (const float*)d_in[2];  // [S, Q, P]
    const float* hr_param    = (const float*)d_in[3];  // [S]
    const int N = in_sizes[1];
    const int nblocks = (N + BLK_ROWS - 1) / BLK_ROWS;  // 1563

    char* ws = (char*)d_ws;
    double* partials = (double*)ws;
    int*   cnt = (int*)(ws + WS_CNT_OFF);
    float* HP  = (float*)(ws + WS_HP_OFF);
    float* hrv = (float*)(ws + WS_HRV_OFF);
    float* out = (float*)d_out;

    const int pre_blocks = (N_S * N_Q + THREADS - 1) / THREADS;  // 13
    precompute_kernel<<<pre_blocks, THREADS, 0, stream>>>(heads_param, hr_param,
                                                          HP, hrv, cnt);
    main_kernel<<<nblocks, THREADS, 0, stream>>>(A, coeff, HP, hrv, partials,
                                                 cnt, out, N);
}